// Round 8
// baseline (241.529 us; speedup 1.0000x reference)
//
#include <hip/hip_runtime.h>
#include <math.h>

#define NU_F 0.0031830988618379067f
#define KTANH 2.885390082f   // 2*log2(e)

typedef _Float16 f16x8 __attribute__((ext_vector_type(8)));
typedef float    f32x4 __attribute__((ext_vector_type(4)));

// tanh from PRE-SCALED argument zs = 2*log2(e)*z:
// tanh(z) = 1 - 2/(exp2(zs)+1); 4 VALU (2 transcendental)
__device__ __forceinline__ float tanh_pre(float zs) {
    float e = __builtin_amdgcn_exp2f(zs);
    float r = __builtin_amdgcn_rcpf(e + 1.0f);
    return fmaf(-2.0f, r, 1.0f);
}

// pack two f32 -> f16x2 in one u32 (v_cvt_pkrtz_f32_f16), low16 = a
__device__ __forceinline__ unsigned pkf16(float a, float b) {
    auto v = __builtin_amdgcn_cvt_pkrtz(a, b);   // __fp16 ext_vector(2)
    return __builtin_bit_cast(unsigned, v);
}

// LDS-only barrier: order LDS ops across waves WITHOUT draining vmcnt.
__device__ __forceinline__ void lds_barrier() {
    asm volatile("s_waitcnt lgkmcnt(0)" ::: "memory");
    __builtin_amdgcn_s_barrier();
}

// ---------------------------------------------------------------------------
// Prep (gather-read, COALESCED-write), channel-QUAD map (round-0 original):
//   dst = fid*512 + lane*8 + jj ; fid = (l*8+nt)*4+ks ; lane = q*16+nn
//   k = ks*32 + q*8 + jj ; c = (nt>>2)*64 + nn*4 + (nt&3)
// N-half nh = nt>>2, quad-tile j = nt&3: wave (nh) owns tiles nh*4..+3,
// thread col nn owns channels nh*64 + nn*4 + {0..3}.
// ---------------------------------------------------------------------------
__global__ void prep_wfrag(const float* __restrict__ Whid, _Float16* __restrict__ wcf)
{
    const int t    = blockIdx.x * 256 + threadIdx.x;   // 0 .. 14335
    const int lane = t & 63;
    const int fid  = t >> 6;          // (l*8 + nt)*4 + ks, 0..223
    const int ks = fid & 3;
    const int nt = (fid >> 2) & 7;
    const int l  = fid >> 5;
    const int q  = lane >> 4;
    const int nn = lane & 15;
    const int c  = ((nt >> 2) << 6) + nn * 4 + (nt & 3);
    const int k0 = ks * 32 + q * 8;
    const float* src = Whid + l * 16384 + k0 * 128 + c;
    f16x8 v;
    #pragma unroll
    for (int jj = 0; jj < 8; ++jj)
        v[jj] = (_Float16)src[jj * 128];
    *(f16x8*)(wcf + (size_t)t * 8) = v;
}

#define HR 68
#define MFMA(A, B, C) __builtin_amdgcn_mfma_f32_16x16x32_f16((A), (B), (C), 0, 0, 0)

// ---------------------------------------------------------------------------
// Unified K-loop: acc[t][j] over 4 row-tiles (rows t*16+lm) x 4 N-tiles.
// Per wave: 16 ds_read_b128 + 12 global B loads (+4 prefetched) + 64 MFMA.
// Works for deriv (t = jet state) and value (t = m-tile) identically.
// ---------------------------------------------------------------------------
__device__ __forceinline__ void kloop44(f32x4 (&acc)[4][4],
        const unsigned* __restrict__ Hc,
        const f16x8 (&cB)[4],
        const _Float16* __restrict__ pbase,
        int lm, int lq)
{
    #pragma unroll
    for (int t = 0; t < 4; ++t)
        #pragma unroll
        for (int j = 0; j < 4; ++j) acc[t][j] = (f32x4){0.f, 0.f, 0.f, 0.f};

    {   // ks = 0: B quads from the cross-layer prefetch registers
        const int ro = lq * 4;
        const f16x8 a0 = *(const f16x8*)&Hc[(0 * 16 + lm) * HR + ro];
        const f16x8 a1 = *(const f16x8*)&Hc[(1 * 16 + lm) * HR + ro];
        const f16x8 a2 = *(const f16x8*)&Hc[(2 * 16 + lm) * HR + ro];
        const f16x8 a3 = *(const f16x8*)&Hc[(3 * 16 + lm) * HR + ro];
        #pragma unroll
        for (int j = 0; j < 4; ++j) {
            acc[0][j] = MFMA(a0, cB[j], acc[0][j]);
            acc[1][j] = MFMA(a1, cB[j], acc[1][j]);
            acc[2][j] = MFMA(a2, cB[j], acc[2][j]);
            acc[3][j] = MFMA(a3, cB[j], acc[3][j]);
        }
    }
    #pragma unroll
    for (int ks = 1; ks < 4; ++ks) {
        const int ro = ks * 16 + lq * 4;
        const f16x8 a0 = *(const f16x8*)&Hc[(0 * 16 + lm) * HR + ro];
        const f16x8 a1 = *(const f16x8*)&Hc[(1 * 16 + lm) * HR + ro];
        const f16x8 a2 = *(const f16x8*)&Hc[(2 * 16 + lm) * HR + ro];
        const f16x8 a3 = *(const f16x8*)&Hc[(3 * 16 + lm) * HR + ro];
        const f16x8 b0 = *(const f16x8*)(pbase + 0 * 2048 + ks * 512);
        const f16x8 b1 = *(const f16x8*)(pbase + 1 * 2048 + ks * 512);
        const f16x8 b2 = *(const f16x8*)(pbase + 2 * 2048 + ks * 512);
        const f16x8 b3 = *(const f16x8*)(pbase + 3 * 2048 + ks * 512);
        acc[0][0] = MFMA(a0, b0, acc[0][0]);
        acc[1][0] = MFMA(a1, b0, acc[1][0]);
        acc[2][0] = MFMA(a2, b0, acc[2][0]);
        acc[3][0] = MFMA(a3, b0, acc[3][0]);
        acc[0][1] = MFMA(a0, b1, acc[0][1]);
        acc[1][1] = MFMA(a1, b1, acc[1][1]);
        acc[2][1] = MFMA(a2, b1, acc[2][1]);
        acc[3][1] = MFMA(a3, b1, acc[3][1]);
        acc[0][2] = MFMA(a0, b2, acc[0][2]);
        acc[1][2] = MFMA(a1, b2, acc[1][2]);
        acc[2][2] = MFMA(a2, b2, acc[2][2]);
        acc[3][2] = MFMA(a3, b2, acc[3][2]);
        acc[0][3] = MFMA(a0, b3, acc[0][3]);
        acc[1][3] = MFMA(a1, b3, acc[1][3]);
        acc[2][3] = MFMA(a2, b3, acc[2][3]);
        acc[3][3] = MFMA(a3, b3, acc[3][3]);
    }
}

// Derivative jet epilogue: acc[state][j] -> H rows s*16+p, quad uint2 writes.
__device__ __forceinline__ void epi_deriv4(const f32x4 (&acc)[4][4],
        const float4 bt, unsigned* __restrict__ Hn, int lq, int wc)
{
    const float bbs[4] = {bt.x * KTANH, bt.y * KTANH, bt.z * KTANH, bt.w * KTANH};
    #pragma unroll
    for (int r = 0; r < 4; ++r) {
        const int p = lq * 4 + r;
        float h[4][4];   // [j][state]
        #pragma unroll
        for (int j = 0; j < 4; ++j) {
            const float zx  = acc[1][j][r];
            const float zt  = acc[2][j][r];
            const float zxx = acc[3][j][r];
            const float y = tanh_pre(fmaf(acc[0][j][r], KTANH, bbs[j]));
            const float d = fmaf(-y, y, 1.f);
            const float m = d * zx;
            h[j][0] = y;
            h[j][1] = m;
            h[j][2] = d * zt;
            h[j][3] = fmaf(d, zxx, -2.f * (y * m) * zx);
        }
        #pragma unroll
        for (int s = 0; s < 4; ++s) {
            uint2 w;
            w.x = pkf16(h[0][s], h[1][s]);
            w.y = pkf16(h[2][s], h[3][s]);
            *(uint2*)&Hn[(s * 16 + p) * HR + wc] = w;
        }
    }
}

// Value epilogue: acc[mt][j] -> H rows mt*16+p, quad uint2 writes.
__device__ __forceinline__ void epi_val4(const f32x4 (&acc)[4][4],
        const float4 bt, unsigned* __restrict__ Hn, int lq, int wc)
{
    const float bbs[4] = {bt.x * KTANH, bt.y * KTANH, bt.z * KTANH, bt.w * KTANH};
    #pragma unroll
    for (int mt = 0; mt < 4; ++mt) {
        #pragma unroll
        for (int r = 0; r < 4; ++r) {
            const int p = mt * 16 + lq * 4 + r;
            float y[4];
            #pragma unroll
            for (int j = 0; j < 4; ++j)
                y[j] = tanh_pre(fmaf(acc[mt][j][r], KTANH, bbs[j]));
            uint2 w;
            w.x = pkf16(y[0], y[1]);
            w.y = pkf16(y[2], y[3]);
            *(uint2*)&Hn[p * HR + wc] = w;
        }
    }
}

// ---------------------------------------------------------------------------
// Fused kernel, 256 thr = 4 waves, TWO independent problems per block.
// Wave wv: problem g = wv>>1, N-half nh = wv&1 (4 N-tiles, 64 channels,
// channel-QUAD map ch = nh*64 + nn*4 + j). Each wave covers ALL 64 M-rows:
// per problem-layer LDS = 32 ds_read_b128 + 32 ds_write_b64 — HALF of the
// r6 structure's read traffic (LDS-port model: 108 -> ~61 us) at the same
// per-problem B traffic. Two lds_barriers per layer (in-place H update).
// acc[4][4] = 64 f32 -> __launch_bounds__(256,3) (the 128-cap of (,4)
// spilled in round 4).
// ---------------------------------------------------------------------------
__global__ __launch_bounds__(256, 3)
void pinn_fused(const float* __restrict__ xf,
                const float* __restrict__ x0,  const float* __restrict__ xbl,
                const float* __restrict__ xbr,
                const float* __restrict__ Win,  const float* __restrict__ bin,
                const float* __restrict__ bhid,
                const float* __restrict__ Wout, const float* __restrict__ bout,
                const _Float16* __restrict__ wcf,
                float* __restrict__ out)
{
    __shared__ unsigned Hh[2][64 * HR];   // [0]=H_A, [1]=H_B
    __shared__ float xpt[256];
    __shared__ float pbuf[512];
    __shared__ float dots[128];

    const int tid  = threadIdx.x;
    const int lane = tid & 63;
    const int wv   = tid >> 6;
    const int g    = wv >> 1;          // problem 0/1
    const int nh   = wv & 1;           // N-half: channels nh*64..+63
    const int lm   = lane & 15;
    const int lq   = lane >> 4;
    const int blk  = blockIdx.x;
    const bool isv = (blk >= 4096);

    if (!isv) {
        if (tid < 64) xpt[tid] = xf[blk * 64 + tid];   // A: pts 0-15, B: 16-31
    } else {
        const int vb = blk - 4096;                     // 0..63
        const int vp = vb * 2 + (tid >> 7);            // 64-pt value sub-block
        const float* src = (vp < 64) ? (x0 + vp * 128)
                         : (vp < 96) ? (xbl + (vp - 64) * 128)
                                     : (xbr + (vp - 96) * 128);
        xpt[tid] = src[tid & 127];
    }

    // ---- prologue prefetch: layer-0 ks=0 B quads + bias quad ----
    const _Float16* pbase = wcf + nh * 8192 + lane * 8;
    const float* bptr = bhid + nh * 64 + lm * 4;
    f16x8 cB[4];
    #pragma unroll
    for (int j = 0; j < 4; ++j) cB[j] = *(const f16x8*)(pbase + j * 2048);
    float4 btc = *(const float4*)bptr;

    __syncthreads();   // xpt ready

    // ---- input layer: thread owns channel pair cp; fill H_A and H_B ----
    const int cp = tid & 63;
    {
        const float2 w01 = *(const float2*)&Win[cp * 2];
        const float2 w11 = *(const float2*)&Win[128 + cp * 2];
        const float2 bb  = *(const float2*)&bin[cp * 2];
        const float w01sx = w01.x * KTANH, w01sy = w01.y * KTANH;
        const float w11sx = w11.x * KTANH, w11sy = w11.y * KTANH;
        const float bbsx  = bb.x  * KTANH, bbsy  = bb.y  * KTANH;
        if (!isv) {
            #pragma unroll
            for (int gg = 0; gg < 2; ++gg) {
                const int xo = gg * 32;
                const int p0 = wv * 4;
                #pragma unroll
                for (int i = 0; i < 4; ++i) {
                    const int p = p0 + i;
                    const float x = xpt[xo + 2 * p], tt = xpt[xo + 2 * p + 1];
                    const float ya = tanh_pre(fmaf(x, w01sx, fmaf(tt, w11sx, bbsx)));
                    const float yb = tanh_pre(fmaf(x, w01sy, fmaf(tt, w11sy, bbsy)));
                    const float da = 1.f - ya * ya, db = 1.f - yb * yb;
                    unsigned* H = Hh[gg];
                    H[(0 * 16 + p) * HR + cp] = pkf16(ya, yb);
                    H[(1 * 16 + p) * HR + cp] = pkf16(da * w01.x, db * w01.y);
                    H[(2 * 16 + p) * HR + cp] = pkf16(da * w11.x, db * w11.y);
                    H[(3 * 16 + p) * HR + cp] =
                        pkf16(-2.f * ya * da * w01.x * w01.x,
                              -2.f * yb * db * w01.y * w01.y);
                }
            }
        } else {
            #pragma unroll
            for (int gg = 0; gg < 2; ++gg) {
                const int xo = gg * 128;
                const int p0 = wv * 16;
                #pragma unroll
                for (int i = 0; i < 16; ++i) {
                    const int p = p0 + i;
                    const float x = xpt[xo + 2 * p], tt = xpt[xo + 2 * p + 1];
                    const float ya = tanh_pre(fmaf(x, w01sx, fmaf(tt, w11sx, bbsx)));
                    const float yb = tanh_pre(fmaf(x, w01sy, fmaf(tt, w11sy, bbsy)));
                    Hh[gg][p * HR + cp] = pkf16(ya, yb);
                }
            }
        }
    }
    lds_barrier();

    const int wc = nh * 32 + lm * 2;   // epilogue dword column (channel quad)
    unsigned* Hg = Hh[g];
    f32x4 acc[4][4];

    if (!isv) {
        // ================= derivative path =================
        for (int l = 0; l < 7; ++l) {
            kloop44(acc, Hg, cB, pbase, lm, lq);
            const float4 bt = btc;
            // depth-1 prefetch of next layer's ks=0 quads + bias
            pbase += 16384;
            if (l < 6) {
                #pragma unroll
                for (int j = 0; j < 4; ++j)
                    cB[j] = *(const f16x8*)(pbase + j * 2048);
                btc = *(const float4*)(bptr + 128);
                bptr += 128;
            }
            lds_barrier();                 // all K-loop reads of Hg done
            epi_deriv4(acc, bt, Hg, lq, wc);
            lds_barrier();                 // in-place H update visible
        }
    } else {
        // ================= value-only path =================
        for (int l = 0; l < 7; ++l) {
            kloop44(acc, Hg, cB, pbase, lm, lq);
            const float4 bt = btc;
            pbase += 16384;
            if (l < 6) {
                #pragma unroll
                for (int j = 0; j < 4; ++j)
                    cB[j] = *(const f16x8*)(pbase + j * 2048);
                btc = *(const float4*)(bptr + 128);
                bptr += 128;
            }
            lds_barrier();
            epi_val4(acc, bt, Hg, lq, wc);
            lds_barrier();
        }
    }

    // ---- output layer: both problems ----
    {
        const int st = lane;           // H row 0..63
        const int cb = wv * 16;        // 16 dwords = 32 channels per chunk
        float pA = 0.f, pB = 0.f;
        #pragma unroll
        for (int c8 = 0; c8 < 4; ++c8) {
            const f16x8 hA = *(const f16x8*)&Hh[0][st * HR + cb + c8 * 4];
            const f16x8 hB = *(const f16x8*)&Hh[1][st * HR + cb + c8 * 4];
            const float4 w1 = *(const float4*)&Wout[wv * 32 + c8 * 8];
            const float4 w2 = *(const float4*)&Wout[wv * 32 + c8 * 8 + 4];
            pA = fmaf((float)hA[0], w1.x, pA);
            pA = fmaf((float)hA[1], w1.y, pA);
            pA = fmaf((float)hA[2], w1.z, pA);
            pA = fmaf((float)hA[3], w1.w, pA);
            pA = fmaf((float)hA[4], w2.x, pA);
            pA = fmaf((float)hA[5], w2.y, pA);
            pA = fmaf((float)hA[6], w2.z, pA);
            pA = fmaf((float)hA[7], w2.w, pA);
            pB = fmaf((float)hB[0], w1.x, pB);
            pB = fmaf((float)hB[1], w1.y, pB);
            pB = fmaf((float)hB[2], w1.z, pB);
            pB = fmaf((float)hB[3], w1.w, pB);
            pB = fmaf((float)hB[4], w2.x, pB);
            pB = fmaf((float)hB[5], w2.y, pB);
            pB = fmaf((float)hB[6], w2.z, pB);
            pB = fmaf((float)hB[7], w2.w, pB);
        }
        pbuf[wv * 64 + st] = pA;
        pbuf[256 + wv * 64 + st] = pB;
    }
    lds_barrier();
    if (tid < 128) {
        const float* q = pbuf + (tid >> 6) * 256;
        const int t = tid & 63;
        dots[tid] = (q[t] + q[64 + t]) + (q[128 + t] + q[192 + t]);
    }
    lds_barrier();
    if (!isv) {
        if (tid < 16) {
            const float u = dots[tid] + bout[0];
            out[8192 + blk * 32 + tid] =
                dots[32 + tid] + u * dots[16 + tid] - NU_F * dots[48 + tid];
        } else if (tid >= 64 && tid < 80) {
            const int t = tid - 64;
            const float u = dots[64 + t] + bout[0];
            out[8192 + blk * 32 + 16 + t] =
                dots[96 + t] + u * dots[80 + t] - NU_F * dots[112 + t];
        }
    } else {
        const int vb = blk - 4096;
        if (tid < 128)
            out[vb * 128 + tid] = dots[tid] + bout[0];
    }
}

extern "C" void kernel_launch(void* const* d_in, const int* in_sizes, int n_in,
                              void* d_out, int out_size, void* d_ws, size_t ws_size,
                              hipStream_t stream) {
    (void)in_sizes; (void)n_in; (void)ws_size; (void)out_size;
    const float* xf   = (const float*)d_in[0];
    const float* x0   = (const float*)d_in[1];
    const float* xbl  = (const float*)d_in[2];
    const float* xbr  = (const float*)d_in[3];
    const float* Win  = (const float*)d_in[4];
    const float* bin  = (const float*)d_in[5];
    const float* Whid = (const float*)d_in[6];
    const float* bhid = (const float*)d_in[7];
    const float* Wout = (const float*)d_in[8];
    const float* bout = (const float*)d_in[9];
    float* out = (float*)d_out;

    _Float16* wcf = (_Float16*)d_ws;   // 7*128*128 f16 = 224 KiB

    hipLaunchKernelGGL(prep_wfrag, dim3(14336 / 256), dim3(256), 0, stream,
                       Whid, wcf);
    hipLaunchKernelGGL(pinn_fused, dim3(4096 + 64), dim3(256), 0, stream,
                       xf, x0, xbl, xbr, Win, bin, bhid, Wout, bout, wcf, out);
}

// Round 9
// 216.396 us; speedup vs baseline: 1.1161x; 1.1161x over previous
//
#include <hip/hip_runtime.h>
#include <math.h>

#define NU_F 0.0031830988618379067f
#define KTANH 2.885390082f   // 2*log2(e)

typedef _Float16 f16x8 __attribute__((ext_vector_type(8)));
typedef float    f32x4 __attribute__((ext_vector_type(4)));

// tanh from PRE-SCALED argument zs = 2*log2(e)*z:
// tanh(z) = 1 - 2/(exp2(zs)+1); 4 VALU (2 transcendental)
__device__ __forceinline__ float tanh_pre(float zs) {
    float e = __builtin_amdgcn_exp2f(zs);
    float r = __builtin_amdgcn_rcpf(e + 1.0f);
    return fmaf(-2.0f, r, 1.0f);
}

// pack two f32 -> f16x2 in one u32 (v_cvt_pkrtz_f32_f16), low16 = a
__device__ __forceinline__ unsigned pkf16(float a, float b) {
    auto v = __builtin_amdgcn_cvt_pkrtz(a, b);   // __fp16 ext_vector(2)
    return __builtin_bit_cast(unsigned, v);
}

// LDS-only barrier: order LDS ops across waves WITHOUT draining vmcnt,
// so prefetched global B loads stay in flight across layer boundaries.
__device__ __forceinline__ void lds_barrier() {
    asm volatile("s_waitcnt lgkmcnt(0)" ::: "memory");
    __builtin_amdgcn_s_barrier();
}

// ---------------------------------------------------------------------------
// Prep (gather-read, COALESCED-write): thread t owns dst dwords t*8..+7.
//   dst = fid*512 + lane*8 + jj ; fid = (l*8+nt)*4+ks ; lane = q*16+nn
//   k = ks*32 + q*8 + jj
// channel-PAIR map (4 waves x 2 tiles): c = (nt>>1)*32 + nn*2 + (nt&1)
// (wave wv owns tiles 2wv,2wv+1 -> channels wv*32 + nn*2 + j)
// ---------------------------------------------------------------------------
__global__ void prep_wfrag(const float* __restrict__ Whid, _Float16* __restrict__ wcf)
{
    const int t    = blockIdx.x * 256 + threadIdx.x;   // 0 .. 14335
    const int lane = t & 63;
    const int fid  = t >> 6;          // (l*8 + nt)*4 + ks, 0..223
    const int ks = fid & 3;
    const int nt = (fid >> 2) & 7;
    const int l  = fid >> 5;
    const int q  = lane >> 4;
    const int nn = lane & 15;
    const int c  = ((nt >> 1) << 5) + nn * 2 + (nt & 1);
    const int k0 = ks * 32 + q * 8;
    const float* src = Whid + l * 16384 + k0 * 128 + c;
    f16x8 v;
    #pragma unroll
    for (int jj = 0; jj < 8; ++jj)
        v[jj] = (_Float16)src[jj * 128];
    *(f16x8*)(wcf + (size_t)t * 8) = v;
}

#define HR 68
#define MFMA(A, B, C) __builtin_amdgcn_mfma_f32_16x16x32_f16((A), (B), (C), 0, 0, 0)

// ---------------------------------------------------------------------------
// Fused kernel, 256 thr = 4 waves; wave wv owns N-tiles 2wv,2wv+1
// (channels wv*32 + nn*2 + {0,1}).  Round-6 winner (153.7 us) plus:
//  - T5: s_setprio(1) around the MFMA cluster (independent blocks on the
//    CU sit at different phases -> kloop waves preempt epilogue waves)
//  - B prefetch depth extended to ks in {0,1} (+16 VGPR, no spill risk)
// Structure: H double-buffered, ONE lds_barrier per layer (no vmcnt
// drain), depth-1 cross-layer prefetch of next layer's ks={0,1} + bias.
// ---------------------------------------------------------------------------
__global__ __launch_bounds__(256, 4)
void pinn_fused(const float* __restrict__ xf,
                const float* __restrict__ x0,  const float* __restrict__ xbl,
                const float* __restrict__ xbr,
                const float* __restrict__ Win,  const float* __restrict__ bin,
                const float* __restrict__ bhid,
                const float* __restrict__ Wout, const float* __restrict__ bout,
                const _Float16* __restrict__ wcf,
                float* __restrict__ out)
{
    __shared__ unsigned Hh[2][64 * HR];
    __shared__ float xpt[128];
    __shared__ float pbuf[256];
    __shared__ float dots[64];

    const int tid  = threadIdx.x;
    const int lane = tid & 63;
    const int wv   = tid >> 6;         // wave 0..3 -> N-tiles 2wv,2wv+1
    const int lm   = lane & 15;
    const int lq   = lane >> 4;
    const int blk  = blockIdx.x;
    const bool isv = (blk >= 8192);

    if (!isv) {
        if (tid < 32) xpt[tid] = xf[blk * 32 + tid];
    } else {
        if (tid < 128) {
            const int vb = blk - 8192;
            const float* src = (vb < 64) ? (x0 + vb * 128)
                             : (vb < 96) ? (xbl + (vb - 64) * 128)
                                         : (xbr + (vb - 96) * 128);
            xpt[tid] = src[tid];
        }
    }

    // ---- prologue prefetch: layer-0 ks={0,1} B pairs + bias (~34 VGPR) ----
    const _Float16* pb0 = wcf + (wv * 2 + 0) * 2048 + lane * 8;
    const _Float16* pb1 = wcf + (wv * 2 + 1) * 2048 + lane * 8;
    const float* bptr = bhid + wv * 32 + lm * 2;
    f16x8 cB0  = *(const f16x8*)pb0;
    f16x8 cB1  = *(const f16x8*)pb1;
    f16x8 cB0b = *(const f16x8*)(pb0 + 512);
    f16x8 cB1b = *(const f16x8*)(pb1 + 512);
    float2 btc = *(const float2*)bptr;

    __syncthreads();   // xpt ready (full barrier: global->LDS staging above)

    // ---- input layer: thread owns channel pair cp -> H buffer 0 ----
    const int cp = tid & 63;
    {
        const float2 w01 = *(const float2*)&Win[cp * 2];
        const float2 w11 = *(const float2*)&Win[128 + cp * 2];
        const float2 bb  = *(const float2*)&bin[cp * 2];
        const float w01sx = w01.x * KTANH, w01sy = w01.y * KTANH;
        const float w11sx = w11.x * KTANH, w11sy = w11.y * KTANH;
        const float bbsx  = bb.x  * KTANH, bbsy  = bb.y  * KTANH;
        if (!isv) {
            const int p0 = wv * 4;
            #pragma unroll
            for (int i = 0; i < 4; ++i) {
                const int p = p0 + i;
                const float x = xpt[2 * p], tt = xpt[2 * p + 1];
                const float ya = tanh_pre(fmaf(x, w01sx, fmaf(tt, w11sx, bbsx)));
                const float yb = tanh_pre(fmaf(x, w01sy, fmaf(tt, w11sy, bbsy)));
                const float da = 1.f - ya * ya, db = 1.f - yb * yb;
                Hh[0][(0 * 16 + p) * HR + cp] = pkf16(ya, yb);
                Hh[0][(1 * 16 + p) * HR + cp] = pkf16(da * w01.x, db * w01.y);
                Hh[0][(2 * 16 + p) * HR + cp] = pkf16(da * w11.x, db * w11.y);
                Hh[0][(3 * 16 + p) * HR + cp] =
                    pkf16(-2.f * ya * da * w01.x * w01.x,
                          -2.f * yb * db * w01.y * w01.y);
            }
        } else {
            const int p0 = wv * 16;
            #pragma unroll
            for (int i = 0; i < 16; ++i) {
                const int p = p0 + i;
                const float x = xpt[2 * p], tt = xpt[2 * p + 1];
                const float ya = tanh_pre(fmaf(x, w01sx, fmaf(tt, w11sx, bbsx)));
                const float yb = tanh_pre(fmaf(x, w01sy, fmaf(tt, w11sy, bbsy)));
                Hh[0][p * HR + cp] = pkf16(ya, yb);
            }
        }
    }
    lds_barrier();

    const int wc = wv * 16 + lm;   // epilogue dword column (channel pair)

    if (!isv) {
        // ================= derivative path =================
        for (int l = 0; l < 7; ++l) {
            const unsigned* Hc = Hh[l & 1];
            unsigned*       Hn = Hh[(l & 1) ^ 1];
            const float bbs0 = btc.x * KTANH, bbs1 = btc.y * KTANH;

            f32x4 acc[4][2];   // [state][tile j]
            #pragma unroll
            for (int s = 0; s < 4; ++s)
                #pragma unroll
                for (int j = 0; j < 2; ++j) acc[s][j] = (f32x4){0.f, 0.f, 0.f, 0.f};

            __builtin_amdgcn_s_setprio(1);
            {   // ks = 0 & 1: B pairs from the cross-barrier prefetch regs
                const int ro = lq * 4;
                const f16x8 ah0 = *(const f16x8*)&Hc[(0 * 16 + lm) * HR + ro];
                const f16x8 ah1 = *(const f16x8*)&Hc[(1 * 16 + lm) * HR + ro];
                const f16x8 ah2 = *(const f16x8*)&Hc[(2 * 16 + lm) * HR + ro];
                const f16x8 ah3 = *(const f16x8*)&Hc[(3 * 16 + lm) * HR + ro];
                acc[0][0] = MFMA(ah0, cB0, acc[0][0]);
                acc[1][0] = MFMA(ah1, cB0, acc[1][0]);
                acc[2][0] = MFMA(ah2, cB0, acc[2][0]);
                acc[3][0] = MFMA(ah3, cB0, acc[3][0]);
                acc[0][1] = MFMA(ah0, cB1, acc[0][1]);
                acc[1][1] = MFMA(ah1, cB1, acc[1][1]);
                acc[2][1] = MFMA(ah2, cB1, acc[2][1]);
                acc[3][1] = MFMA(ah3, cB1, acc[3][1]);
            }
            {
                const int ro = 16 + lq * 4;
                const f16x8 ah0 = *(const f16x8*)&Hc[(0 * 16 + lm) * HR + ro];
                const f16x8 ah1 = *(const f16x8*)&Hc[(1 * 16 + lm) * HR + ro];
                const f16x8 ah2 = *(const f16x8*)&Hc[(2 * 16 + lm) * HR + ro];
                const f16x8 ah3 = *(const f16x8*)&Hc[(3 * 16 + lm) * HR + ro];
                acc[0][0] = MFMA(ah0, cB0b, acc[0][0]);
                acc[1][0] = MFMA(ah1, cB0b, acc[1][0]);
                acc[2][0] = MFMA(ah2, cB0b, acc[2][0]);
                acc[3][0] = MFMA(ah3, cB0b, acc[3][0]);
                acc[0][1] = MFMA(ah0, cB1b, acc[0][1]);
                acc[1][1] = MFMA(ah1, cB1b, acc[1][1]);
                acc[2][1] = MFMA(ah2, cB1b, acc[2][1]);
                acc[3][1] = MFMA(ah3, cB1b, acc[3][1]);
            }
            #pragma unroll
            for (int ks = 2; ks < 4; ++ks) {
                const int ro = ks * 16 + lq * 4;
                const f16x8 ah0 = *(const f16x8*)&Hc[(0 * 16 + lm) * HR + ro];
                const f16x8 ah1 = *(const f16x8*)&Hc[(1 * 16 + lm) * HR + ro];
                const f16x8 ah2 = *(const f16x8*)&Hc[(2 * 16 + lm) * HR + ro];
                const f16x8 ah3 = *(const f16x8*)&Hc[(3 * 16 + lm) * HR + ro];
                const f16x8 b0 = *(const f16x8*)(pb0 + ks * 512);
                const f16x8 b1 = *(const f16x8*)(pb1 + ks * 512);
                acc[0][0] = MFMA(ah0, b0, acc[0][0]);
                acc[1][0] = MFMA(ah1, b0, acc[1][0]);
                acc[2][0] = MFMA(ah2, b0, acc[2][0]);
                acc[3][0] = MFMA(ah3, b0, acc[3][0]);
                acc[0][1] = MFMA(ah0, b1, acc[0][1]);
                acc[1][1] = MFMA(ah1, b1, acc[1][1]);
                acc[2][1] = MFMA(ah2, b1, acc[2][1]);
                acc[3][1] = MFMA(ah3, b1, acc[3][1]);
            }
            __builtin_amdgcn_s_setprio(0);

            // depth-1 prefetch: next layer's ks={0,1} pairs + bias (hides
            // under the epilogue; survives lds_barrier — no vmcnt drain)
            pb0 += 16384; pb1 += 16384;
            if (l < 6) {
                cB0  = *(const f16x8*)pb0;
                cB1  = *(const f16x8*)pb1;
                cB0b = *(const f16x8*)(pb0 + 512);
                cB1b = *(const f16x8*)(pb1 + 512);
                btc = *(const float2*)(bptr + 128);
                bptr += 128;
            }

            #pragma unroll
            for (int r = 0; r < 4; ++r) {
                const int p = lq * 4 + r;
                float h[2][4];   // [tile j][state]
                #pragma unroll
                for (int j = 0; j < 2; ++j) {
                    const float zx  = acc[1][j][r];
                    const float zt  = acc[2][j][r];
                    const float zxx = acc[3][j][r];
                    const float y = tanh_pre(fmaf(acc[0][j][r], KTANH,
                                                  j ? bbs1 : bbs0));
                    const float d = fmaf(-y, y, 1.f);
                    const float m = d * zx;
                    h[j][0] = y;
                    h[j][1] = m;
                    h[j][2] = d * zt;
                    h[j][3] = fmaf(d, zxx, -2.f * (y * m) * zx);
                }
                #pragma unroll
                for (int s = 0; s < 4; ++s)
                    Hn[(s * 16 + p) * HR + wc] = pkf16(h[0][s], h[1][s]);
            }
            lds_barrier();   // Hn complete before it becomes Hc
        }
    } else {
        // ================= value-only path =================
        for (int l = 0; l < 7; ++l) {
            const unsigned* Hc = Hh[l & 1];
            unsigned*       Hn = Hh[(l & 1) ^ 1];
            const float bbs0 = btc.x * KTANH, bbs1 = btc.y * KTANH;

            f32x4 acc[4][2];   // [m-tile][tile j]
            #pragma unroll
            for (int mt = 0; mt < 4; ++mt)
                #pragma unroll
                for (int j = 0; j < 2; ++j) acc[mt][j] = (f32x4){0.f, 0.f, 0.f, 0.f};

            __builtin_amdgcn_s_setprio(1);
            {   // ks = 0 & 1 with prefetched pairs
                const int ro = lq * 4;
                f16x8 ah[4];
                #pragma unroll
                for (int mt = 0; mt < 4; ++mt)
                    ah[mt] = *(const f16x8*)&Hc[(mt * 16 + lm) * HR + ro];
                #pragma unroll
                for (int mt = 0; mt < 4; ++mt) {
                    acc[mt][0] = MFMA(ah[mt], cB0, acc[mt][0]);
                    acc[mt][1] = MFMA(ah[mt], cB1, acc[mt][1]);
                }
            }
            {
                const int ro = 16 + lq * 4;
                f16x8 ah[4];
                #pragma unroll
                for (int mt = 0; mt < 4; ++mt)
                    ah[mt] = *(const f16x8*)&Hc[(mt * 16 + lm) * HR + ro];
                #pragma unroll
                for (int mt = 0; mt < 4; ++mt) {
                    acc[mt][0] = MFMA(ah[mt], cB0b, acc[mt][0]);
                    acc[mt][1] = MFMA(ah[mt], cB1b, acc[mt][1]);
                }
            }
            #pragma unroll
            for (int ks = 2; ks < 4; ++ks) {
                const int ro = ks * 16 + lq * 4;
                f16x8 ah[4];
                #pragma unroll
                for (int mt = 0; mt < 4; ++mt)
                    ah[mt] = *(const f16x8*)&Hc[(mt * 16 + lm) * HR + ro];
                const f16x8 b0 = *(const f16x8*)(pb0 + ks * 512);
                const f16x8 b1 = *(const f16x8*)(pb1 + ks * 512);
                #pragma unroll
                for (int mt = 0; mt < 4; ++mt) {
                    acc[mt][0] = MFMA(ah[mt], b0, acc[mt][0]);
                    acc[mt][1] = MFMA(ah[mt], b1, acc[mt][1]);
                }
            }
            __builtin_amdgcn_s_setprio(0);

            pb0 += 16384; pb1 += 16384;
            if (l < 6) {
                cB0  = *(const f16x8*)pb0;
                cB1  = *(const f16x8*)pb1;
                cB0b = *(const f16x8*)(pb0 + 512);
                cB1b = *(const f16x8*)(pb1 + 512);
                btc = *(const float2*)(bptr + 128);
                bptr += 128;
            }

            #pragma unroll
            for (int mt = 0; mt < 4; ++mt) {
                #pragma unroll
                for (int r = 0; r < 4; ++r) {
                    const int p = mt * 16 + lq * 4 + r;
                    const float y0 = tanh_pre(fmaf(acc[mt][0][r], KTANH, bbs0));
                    const float y1 = tanh_pre(fmaf(acc[mt][1][r], KTANH, bbs1));
                    Hn[p * HR + wc] = pkf16(y0, y1);
                }
            }
            lds_barrier();
        }
    }

    // ---- output layer: read H buffer 1 (after 7 layers: 0->1->...->1) ----
    {
        const int st = lane;           // H row 0..63
        const int cb = wv * 16;        // 16 dwords = 32 channels per chunk
        float part = 0.f;
        #pragma unroll
        for (int c8 = 0; c8 < 4; ++c8) {
            const f16x8 hv = *(const f16x8*)&Hh[1][st * HR + cb + c8 * 4];
            const float4 w1 = *(const float4*)&Wout[wv * 32 + c8 * 8];
            const float4 w2 = *(const float4*)&Wout[wv * 32 + c8 * 8 + 4];
            part = fmaf((float)hv[0], w1.x, part);
            part = fmaf((float)hv[1], w1.y, part);
            part = fmaf((float)hv[2], w1.z, part);
            part = fmaf((float)hv[3], w1.w, part);
            part = fmaf((float)hv[4], w2.x, part);
            part = fmaf((float)hv[5], w2.y, part);
            part = fmaf((float)hv[6], w2.z, part);
            part = fmaf((float)hv[7], w2.w, part);
        }
        pbuf[wv * 64 + st] = part;
    }
    lds_barrier();
    if (tid < 64)
        dots[tid] = (pbuf[tid] + pbuf[64 + tid]) + (pbuf[128 + tid] + pbuf[192 + tid]);
    lds_barrier();
    if (!isv) {
        if (tid < 16) {
            const float u = dots[tid] + bout[0];
            out[8192 + blk * 16 + tid] =
                dots[32 + tid] + u * dots[16 + tid] - NU_F * dots[48 + tid];
        }
    } else {
        if (tid < 64) out[(blk - 8192) * 64 + tid] = dots[tid] + bout[0];
    }
}

extern "C" void kernel_launch(void* const* d_in, const int* in_sizes, int n_in,
                              void* d_out, int out_size, void* d_ws, size_t ws_size,
                              hipStream_t stream) {
    (void)in_sizes; (void)n_in; (void)ws_size; (void)out_size;
    const float* xf   = (const float*)d_in[0];
    const float* x0   = (const float*)d_in[1];
    const float* xbl  = (const float*)d_in[2];
    const float* xbr  = (const float*)d_in[3];
    const float* Win  = (const float*)d_in[4];
    const float* bin  = (const float*)d_in[5];
    const float* Whid = (const float*)d_in[6];
    const float* bhid = (const float*)d_in[7];
    const float* Wout = (const float*)d_in[8];
    const float* bout = (const float*)d_in[9];
    float* out = (float*)d_out;

    _Float16* wcf = (_Float16*)d_ws;   // 7*128*128 f16 = 224 KiB

    hipLaunchKernelGGL(prep_wfrag, dim3(14336 / 256), dim3(256), 0, stream,
                       Whid, wcf);
    hipLaunchKernelGGL(pinn_fused, dim3(8192 + 128), dim3(256), 0, stream,
                       xf, x0, xbl, xbr, Win, bin, bhid, Wout, bout, wcf, out);
}